// Round 9
// baseline (231.842 us; speedup 1.0000x reference)
//
#include <hip/hip_runtime.h>
#include <cstddef>

#define NN 100000
#define DD 128
#define ND (NN * DD)
#define BN_EPS 1e-5f
#define LDA 136                // LDS A row stride in bf16 elems (272 B, 16B-aligned)
#define NREP 16                // stats-accumulator replicas
#define NBKT 392               // scatter buckets: 256 nodes each (392*256 >= NN)
#define BSH 8                  // bucket = col >> 8
#define EPB 4096               // edges per bcnt/k_bin block
#define NT ((NN + 63) / 64)    // 1563 tiles of 64 rows

typedef __bf16 bf16_t;
typedef bf16_t bf16x8 __attribute__((ext_vector_type(8)));
typedef float f32x4 __attribute__((ext_vector_type(4)));
typedef unsigned int uint;
typedef unsigned short ushort;

// ws 4-byte-slot layout:
//   [0, ND/2)            region0: pairs (uint2 x E) pre-gg; hb after
//   [ND/2, ND)           xb   (bf16 x)
//   base3 = ND:
//   csr[16*128], cqr[16*128], bktot[512], bcur[512]  (memset zeroes all),
//   cnt[NN], ptr0[NN], dinv[NN], srow[E], wb[4096 uints]

__device__ __forceinline__ ushort f2b(float f) {
    uint u = __builtin_bit_cast(uint, f);
    u += 0x7FFFu + ((u >> 16) & 1u);          // RNE
    return (ushort)(u >> 16);
}
__device__ __forceinline__ float b2f(uint s) {
    return __builtin_bit_cast(float, s << 16);
}
__device__ __forceinline__ float blo(uint u) {          // low bf16 -> f32
    return __builtin_bit_cast(float, u << 16);
}
__device__ __forceinline__ float bhi(uint u) {          // high bf16 -> f32
    return __builtin_bit_cast(float, u & 0xFFFF0000u);
}

// int64 edge_index => high word of every entry is 0 (ids < 100000).
__device__ __forceinline__ int detect_i64(const int* __restrict__ ei) {
    __shared__ int sflag;
    int t = threadIdx.x;
    if (t < 64) {
        int hi = ei[2 * t + 1];
        unsigned long long b = __ballot(hi == 0);
        if (t == 0) sflag = (b == ~0ull) ? 1 : 0;
    }
    __syncthreads();
    return sflag;
}

// dual-role: blocks [0, nbh) LDS-histogram cols into bucket totals;
// rest pack x and W to bf16.
__global__ __launch_bounds__(256) void k_prep(const int* __restrict__ ei,
                                              int* __restrict__ bktot, int E, int nbh,
                                              const float* __restrict__ x,
                                              uint* __restrict__ xb,
                                              const float* __restrict__ W,
                                              uint* __restrict__ wb) {
    if ((int)blockIdx.x < nbh) {
        int f = detect_i64(ei);
        __shared__ int hist[NBKT];
        int t = threadIdx.x;
        for (int i = t; i < NBKT; i += 256) hist[i] = 0;
        __syncthreads();
        int base = blockIdx.x * EPB;
        int count = min(EPB, E - base);
        for (int i = t; i < count; i += 256) {
            int e = base + i;
            int c = f ? ei[2 * (E + e)] : ei[E + e];
            atomicAdd(&hist[c >> BSH], 1);
        }
        __syncthreads();
        for (int i = t; i < NBKT; i += 256)
            if (hist[i] > 0) atomicAdd(&bktot[i], hist[i]);
        return;
    }
    int i = (blockIdx.x - nbh) * 256 + threadIdx.x;
    const float* src;
    uint* dst;
    int j;
    if (i < ND / 8) { src = x; dst = xb; j = i; }
    else { j = i - ND / 8; if (j >= (DD * DD) / 8) return; src = W; dst = wb; }
    const float4* s4 = (const float4*)src;
    float4 a = s4[2 * j], b = s4[2 * j + 1];
    uint4 o;
    o.x = (uint)f2b(a.x) | ((uint)f2b(a.y) << 16);
    o.y = (uint)f2b(a.z) | ((uint)f2b(a.w) << 16);
    o.z = (uint)f2b(b.x) | ((uint)f2b(b.y) << 16);
    o.w = (uint)f2b(b.z) | ((uint)f2b(b.w) << 16);
    ((uint4*)dst)[j] = o;
}

// partition edges into NBKT destination buckets. Bucket bases computed by a
// redundant per-block LDS scan of bktot; global bcur holds only the
// in-bucket running offset (zero-initialized by memset).
__global__ __launch_bounds__(256) void k_bin(const int* __restrict__ ei,
                                             const int* __restrict__ bktot,
                                             int* __restrict__ bcur,
                                             uint2* __restrict__ pairs, int E) {
    int f = detect_i64(ei);
    __shared__ int bb[NBKT], hist[NBKT], scur[NBKT];
    int t = threadIdx.x;
    for (int i = t; i < NBKT; i += 256) { bb[i] = bktot[i]; hist[i] = 0; }
    __syncthreads();
    if (t == 0) {
        int run = 0;
        for (int i = 0; i < NBKT; ++i) { int v = bb[i]; bb[i] = run; run += v; }
    }
    int base = blockIdx.x * EPB;
    int count = min(EPB, E - base);
    int rr[16], cc[16];
#pragma unroll
    for (int k = 0; k < 16; ++k) {
        int i = t + k * 256;
        if (i < count) {
            int e = base + i;
            int r, c;
            if (f) { r = ei[2 * e]; c = ei[2 * (E + e)]; }
            else   { r = ei[e];     c = ei[E + e]; }
            rr[k] = r; cc[k] = c;
            atomicAdd(&hist[c >> BSH], 1);
        }
    }
    __syncthreads();   // joins t0's scan and the histogram
    for (int i = t; i < NBKT; i += 256)
        if (hist[i] > 0) scur[i] = bb[i] + atomicAdd(&bcur[i], hist[i]);
    __syncthreads();
#pragma unroll
    for (int k = 0; k < 16; ++k) {
        int i = t + k * 256;
        if (i < count) {
            int b = cc[k] >> BSH;
            int pos = atomicAdd(&scur[b], 1);
            pairs[pos] = (uint2){(uint)rr[k], (uint)cc[k]};
        }
    }
}

// one block per bucket (392 blocks, 256 nodes each): LDS histogram + scan ->
// ptr0/cnt/dinv (1 node/thread), then scatter srow with LDS atomics only.
__global__ __launch_bounds__(256) void k_cnt(const uint2* __restrict__ pairs,
                                             const int* __restrict__ bktot,
                                             int* __restrict__ ptr0,
                                             int* __restrict__ cnt,
                                             float* __restrict__ dinv,
                                             int* __restrict__ srow) {
    __shared__ int sbt[NBKT];
    __shared__ int hist[256], scur[256], ls[256];
    __shared__ int se0, se1;
    int b = blockIdx.x;
    int t = threadIdx.x;
    for (int i = t; i < NBKT; i += 256) sbt[i] = bktot[i];
    hist[t] = 0;
    __syncthreads();
    if (t == 0) {
        int run = 0;
        for (int i = 0; i < b; ++i) run += sbt[i];
        se0 = run; se1 = run + sbt[b];
    }
    __syncthreads();
    int e0 = se0, e1 = se1;
    int nodebase = b << BSH;
    for (int i = e0 + t; i < e1; i += 256)
        atomicAdd(&hist[(int)pairs[i].y - nodebase], 1);
    __syncthreads();
    int c1 = hist[t];
    ls[t] = c1;
    __syncthreads();
    for (int o = 1; o < 256; o <<= 1) {
        int v = (t >= o) ? ls[t - o] : 0;
        __syncthreads();
        ls[t] += v;
        __syncthreads();
    }
    int run = ls[t] - c1 + e0;
    int idx = nodebase + t;
    if (idx < NN) {
        ptr0[idx] = run;
        cnt[idx] = c1;
        dinv[idx] = c1 > 0 ? rsqrtf((float)c1) : 0.f;
    }
    scur[t] = run;
    __syncthreads();
    for (int i = e0 + t; i < e1; i += 256) {
        uint2 p = pairs[i];
        int pos = atomicAdd(&scur[(int)p.y - nodebase], 1);
        srow[pos] = (int)p.x;
    }
}

// FUSED gather + GEMM + stats. Block = 8 waves = 512 thr, 64-row tile.
// Gather: dynamic LDS work queue — each wave pops one node and runs the
// proven one-node-per-wave inner loop (per-lane dword row loads, 4-deep,
// chunk-preloaded wj). No max-degree padding, no static-partition tail.
__global__ __launch_bounds__(512, 4) void k_gg(const uint* __restrict__ xb,
                                               const int* __restrict__ srow,
                                               const int* __restrict__ ptr0,
                                               const int* __restrict__ cnt,
                                               const float* __restrict__ dinv,
                                               const ushort* __restrict__ wb,
                                               ushort* __restrict__ hb,
                                               float* __restrict__ csr,
                                               float* __restrict__ cqr) {
    __shared__ ushort sA[64 * LDA];            // 17.4 KB
    __shared__ float cp[8][64], cq[8][64];     // 4 KB
    __shared__ int sS[64], sK[64];
    __shared__ float sD[64];
    __shared__ int qctr;
    int t = threadIdx.x;
    int wave = t >> 6, lane = t & 63;
    int quad = lane >> 4, l16 = lane & 15;
    uint rowbase = (uint)blockIdx.x * 64;

    if (t == 0) qctr = 0;
    if (t < 64) {                               // prefetch node meta into LDS
        int node = (int)rowbase + t;
        bool v = node < NN;
        sS[t] = v ? ptr0[node] : 0;
        sK[t] = v ? cnt[node] : 0;
        sD[t] = v ? dinv[node] : 0.f;
    }
    __syncthreads();

    for (;;) {
        int nl = 0;
        if (lane == 0) nl = atomicAdd(&qctr, 1);
        int ni = __shfl(nl, 0);
        if (ni >= 64) break;
        int s = sS[ni], k = sK[ni];
        float dc = sD[ni];
        float ax = 0.f, ay = 0.f;
        for (int base = 0; base < k; base += 64) {
            int m = min(k - base, 64);
            int rj = 0; float wj = 0.f;
            if (lane < m) { rj = srow[s + base + lane]; wj = dinv[rj]; }
            int j = 0;
            for (; j + 4 <= m; j += 4) {
                int r0 = __shfl(rj, j);     float w0 = __shfl(wj, j);
                int r1 = __shfl(rj, j + 1); float w1 = __shfl(wj, j + 1);
                int r2 = __shfl(rj, j + 2); float w2 = __shfl(wj, j + 2);
                int r3 = __shfl(rj, j + 3); float w3 = __shfl(wj, j + 3);
                uint v0 = xb[((uint)r0 << 6) + (uint)lane];
                uint v1 = xb[((uint)r1 << 6) + (uint)lane];
                uint v2 = xb[((uint)r2 << 6) + (uint)lane];
                uint v3 = xb[((uint)r3 << 6) + (uint)lane];
                ax = fmaf(w0, blo(v0), ax); ay = fmaf(w0, bhi(v0), ay);
                ax = fmaf(w1, blo(v1), ax); ay = fmaf(w1, bhi(v1), ay);
                ax = fmaf(w2, blo(v2), ax); ay = fmaf(w2, bhi(v2), ay);
                ax = fmaf(w3, blo(v3), ax); ay = fmaf(w3, bhi(v3), ay);
            }
            for (; j < m; ++j) {
                int r = __shfl(rj, j);
                float w = __shfl(wj, j);
                uint v = xb[((uint)r << 6) + (uint)lane];
                ax = fmaf(w, blo(v), ax);
                ay = fmaf(w, bhi(v), ay);
            }
        }
        *(uint*)(sA + ni * LDA + lane * 2) =
            (uint)f2b(dc * ax) | ((uint)f2b(dc * ay) << 16);   // zeros for OOB
    }
    __syncthreads();

    // --- GEMM: wave = row-group (wave&3) x ct-half (wave>>2) ---
    int rg = wave & 3, chh = wave >> 2;
    bf16x8 Af[4];
#pragma unroll
    for (int ks = 0; ks < 4; ++ks)
        Af[ks] = __builtin_bit_cast(
            bf16x8, *(const uint4*)(sA + (rg * 16 + l16) * LDA + ks * 32 + quad * 8));

#pragma unroll
    for (int c = 0; c < 4; ++c) {
        int ctg = chh * 4 + c;
        bf16x8 Bf[4];
#pragma unroll
        for (int ks = 0; ks < 4; ++ks)
            Bf[ks] = __builtin_bit_cast(
                bf16x8,
                *(const uint4*)(wb + (uint)(ctg * 16 + l16) * 128 + ks * 32 + quad * 8));
        f32x4 acc = (f32x4){0.f, 0.f, 0.f, 0.f};
#pragma unroll
        for (int ks = 0; ks < 4; ++ks)
            acc = __builtin_amdgcn_mfma_f32_16x16x32_bf16(Af[ks], Bf[ks], acc, 0, 0, 0);
        float ss = 0.f, qq = 0.f;
#pragma unroll
        for (int r = 0; r < 4; ++r) {
            float v = acc[r];
            ss += v; qq += v * v;
            uint row = rowbase + rg * 16 + quad * 4 + r;
            if (row < NN) hb[row * 128u + (uint)(ctg * 16 + l16)] = f2b(v);
        }
        ss += __shfl_xor(ss, 16); ss += __shfl_xor(ss, 32);
        qq += __shfl_xor(qq, 16); qq += __shfl_xor(qq, 32);
        if (quad == 0) { cp[wave][c * 16 + l16] = ss; cq[wave][c * 16 + l16] = qq; }
    }
    __syncthreads();
    if (t < 128) {
        int w0 = (t >> 6) * 4, lc = t & 63;
        float s = cp[w0][lc] + cp[w0 + 1][lc] + cp[w0 + 2][lc] + cp[w0 + 3][lc];
        float q = cq[w0][lc] + cq[w0 + 1][lc] + cq[w0 + 2][lc] + cq[w0 + 3][lc];
        int rep = ((int)blockIdx.x & (NREP - 1)) * 128 + t;
        atomicAdd(&csr[rep], s);
        atomicAdd(&cqr[rep], q);
    }
}

// BN + relu + residual; folds the NREP stat replicas in LDS.
__global__ __launch_bounds__(256) void k_final(const uint* __restrict__ hb,
                                               const uint* __restrict__ xb,
                                               const float* __restrict__ gamma,
                                               const float* __restrict__ beta,
                                               const float* __restrict__ csr,
                                               const float* __restrict__ cqr,
                                               float* __restrict__ out, int out_size) {
    __shared__ float sa[128], sb[128];
    int t = threadIdx.x;
    const float invN = 1.0f / NN;
    if (t < 128) {
        float s = 0.f;
        for (int i = 0; i < NREP; ++i) s += csr[i * 128 + t];
        sa[t] = s * invN;
    } else {
        int c = t - 128;
        float s = 0.f;
        for (int i = 0; i < NREP; ++i) s += cqr[i * 128 + c];
        sb[c] = s * invN;
    }
    __syncthreads();
    if (t < 128) {
        float m = sa[t];
        float var = sb[t] - m * m;
        float inv = rsqrtf(var + BN_EPS);
        float A = inv * gamma[t];
        float B = beta[t] - m * A;
        sa[t] = A; sb[t] = B;
    }
    __syncthreads();

    int c0 = (t & 7) * 16;
    int u8 = blockIdx.x * 512 + t * 2;
    uint4 hv0 = ((const uint4*)hb)[u8], hv1 = ((const uint4*)hb)[u8 + 1];
    uint4 xv0 = ((const uint4*)xb)[u8], xv1 = ((const uint4*)xb)[u8 + 1];
    uint hu[8] = {hv0.x, hv0.y, hv0.z, hv0.w, hv1.x, hv1.y, hv1.z, hv1.w};
    uint xu[8] = {xv0.x, xv0.y, xv0.z, xv0.w, xv1.x, xv1.y, xv1.z, xv1.w};
    float res[16];
#pragma unroll
    for (int p = 0; p < 8; ++p) {
        int c = c0 + p * 2;
        float h0 = blo(hu[p]), h1 = bhi(hu[p]);
        float x0 = blo(xu[p]), x1 = bhi(xu[p]);
        res[2 * p]     = fmaxf(fmaf(h0, sa[c],     sb[c]),     0.f) + x0;
        res[2 * p + 1] = fmaxf(fmaf(h1, sa[c + 1], sb[c + 1]), 0.f) + x1;
    }
    float4* o4 = (float4*)out;
    int ob = blockIdx.x * 1024 + t * 4;
#pragma unroll
    for (int q = 0; q < 4; ++q)
        o4[ob + q] = (float4){res[4 * q], res[4 * q + 1], res[4 * q + 2], res[4 * q + 3]};
    if (blockIdx.x == 0 && t == 0 && out_size > ND) out[ND] = 0.0f;
}

extern "C" void kernel_launch(void* const* d_in, const int* in_sizes, int n_in,
                              void* d_out, int out_size, void* d_ws, size_t ws_size,
                              hipStream_t stream) {
    const float* x     = (const float*)d_in[0];
    const int*   ei    = (const int*)d_in[1];
    const float* W     = (const float*)d_in[2];
    const float* gamma = (const float*)d_in[4];
    const float* beta  = (const float*)d_in[5];
    float* ws = (float*)d_ws;
    float* out = (float*)d_out;

    uint*   region0  = (uint*)ws;                      // pairs, then hb
    uint*   xb       = region0 + ND / 2;
    float*  csr      = (float*)(xb + ND / 2);          // 16*128
    float*  cqr      = csr + NREP * 128;               // 16*128
    int*    bktot    = (int*)(cqr + NREP * 128);       // 512 (zeroed)
    int*    bcur     = bktot + 512;                    // 512 (zeroed)
    int*    cnt      = bcur + 512;                     // NN
    int*    ptr0     = cnt + NN;                       // NN
    float*  dinv     = (float*)(ptr0 + NN);            // NN
    int*    srow     = (int*)(dinv + NN);              // E

    int E = in_sizes[1] / 2;
    uint* wb = (uint*)(srow + E);
    uint2* pairs = (uint2*)region0;

    int nbc = (ND / 8 + (DD * DD) / 8 + 255) / 256;
    int nbin = (E + EPB - 1) / EPB;

    hipMemsetAsync(csr, 0, (size_t)(2 * NREP * 128 + 1024) * 4, stream);
    k_prep<<<nbin + nbc, 256, 0, stream>>>(ei, bktot, E, nbin, x, xb, W, wb);
    k_bin<<<nbin, 256, 0, stream>>>(ei, bktot, bcur, pairs, E);
    k_cnt<<<NBKT, 256, 0, stream>>>(pairs, bktot, ptr0, cnt, dinv, srow);
    k_gg<<<NT, 512, 0, stream>>>(xb, srow, ptr0, cnt, dinv, (const ushort*)wb,
                                 (ushort*)region0, csr, cqr);
    k_final<<<ND / 4096, 256, 0, stream>>>(region0, xb, gamma, beta, csr, cqr,
                                           out, out_size);
}

// Round 10
// 223.228 us; speedup vs baseline: 1.0386x; 1.0386x over previous
//
#include <hip/hip_runtime.h>
#include <cstddef>

#define NN 100000
#define DD 128
#define ND (NN * DD)
#define BN_EPS 1e-5f
#define LDA 136                // LDS A row stride in bf16 elems (272 B, 16B-aligned)
#define NREP 16                // stats-accumulator replicas
#define NBKT 392               // scatter buckets: 256 nodes each (392*256 >= NN)
#define BSH 8                  // bucket = col >> 8
#define EPB 4096               // edges per bcnt/k_bin block
#define NT ((NN + 63) / 64)    // 1563 tiles of 64 rows

typedef __bf16 bf16_t;
typedef bf16_t bf16x8 __attribute__((ext_vector_type(8)));
typedef float f32x4 __attribute__((ext_vector_type(4)));
typedef unsigned int uint;
typedef unsigned short ushort;

// ws 4-byte-slot layout:
//   [0, ND/2)            region0: pairs (uint2 x E) pre-gg; hb after
//   [ND/2, ND)           xb   (bf16 x)
//   base3 = ND:
//   csr[16*128], cqr[16*128], bktot[512], bcur[512]  (memset zeroes all),
//   cnt[NN], ptr0[NN], dinv[NN], srow[E], wb[4096 uints]

__device__ __forceinline__ ushort f2b(float f) {
    uint u = __builtin_bit_cast(uint, f);
    u += 0x7FFFu + ((u >> 16) & 1u);          // RNE
    return (ushort)(u >> 16);
}
__device__ __forceinline__ float b2f(uint s) {
    return __builtin_bit_cast(float, s << 16);
}
__device__ __forceinline__ float blo(uint u) {          // low bf16 -> f32
    return __builtin_bit_cast(float, u << 16);
}
__device__ __forceinline__ float bhi(uint u) {          // high bf16 -> f32
    return __builtin_bit_cast(float, u & 0xFFFF0000u);
}

// int64 edge_index => high word of every entry is 0 (ids < 100000).
__device__ __forceinline__ int detect_i64(const int* __restrict__ ei) {
    __shared__ int sflag;
    int t = threadIdx.x;
    if (t < 64) {
        int hi = ei[2 * t + 1];
        unsigned long long b = __ballot(hi == 0);
        if (t == 0) sflag = (b == ~0ull) ? 1 : 0;
    }
    __syncthreads();
    return sflag;
}

// dual-role: blocks [0, nbh) LDS-histogram cols into bucket totals;
// rest pack x and W to bf16.
__global__ __launch_bounds__(256) void k_prep(const int* __restrict__ ei,
                                              int* __restrict__ bktot, int E, int nbh,
                                              const float* __restrict__ x,
                                              uint* __restrict__ xb,
                                              const float* __restrict__ W,
                                              uint* __restrict__ wb) {
    if ((int)blockIdx.x < nbh) {
        int f = detect_i64(ei);
        __shared__ int hist[NBKT];
        int t = threadIdx.x;
        for (int i = t; i < NBKT; i += 256) hist[i] = 0;
        __syncthreads();
        int base = blockIdx.x * EPB;
        int count = min(EPB, E - base);
        for (int i = t; i < count; i += 256) {
            int e = base + i;
            int c = f ? ei[2 * (E + e)] : ei[E + e];
            atomicAdd(&hist[c >> BSH], 1);
        }
        __syncthreads();
        for (int i = t; i < NBKT; i += 256)
            if (hist[i] > 0) atomicAdd(&bktot[i], hist[i]);
        return;
    }
    int i = (blockIdx.x - nbh) * 256 + threadIdx.x;
    const float* src;
    uint* dst;
    int j;
    if (i < ND / 8) { src = x; dst = xb; j = i; }
    else { j = i - ND / 8; if (j >= (DD * DD) / 8) return; src = W; dst = wb; }
    const float4* s4 = (const float4*)src;
    float4 a = s4[2 * j], b = s4[2 * j + 1];
    uint4 o;
    o.x = (uint)f2b(a.x) | ((uint)f2b(a.y) << 16);
    o.y = (uint)f2b(a.z) | ((uint)f2b(a.w) << 16);
    o.z = (uint)f2b(b.x) | ((uint)f2b(b.y) << 16);
    o.w = (uint)f2b(b.z) | ((uint)f2b(b.w) << 16);
    ((uint4*)dst)[j] = o;
}

// partition edges into NBKT destination buckets. Bucket bases computed by a
// redundant per-block LDS scan of bktot; global bcur holds only the
// in-bucket running offset (zero-initialized by memset).
__global__ __launch_bounds__(256) void k_bin(const int* __restrict__ ei,
                                             const int* __restrict__ bktot,
                                             int* __restrict__ bcur,
                                             uint2* __restrict__ pairs, int E) {
    int f = detect_i64(ei);
    __shared__ int bb[NBKT], hist[NBKT], scur[NBKT];
    int t = threadIdx.x;
    for (int i = t; i < NBKT; i += 256) { bb[i] = bktot[i]; hist[i] = 0; }
    __syncthreads();
    if (t == 0) {
        int run = 0;
        for (int i = 0; i < NBKT; ++i) { int v = bb[i]; bb[i] = run; run += v; }
    }
    int base = blockIdx.x * EPB;
    int count = min(EPB, E - base);
    int rr[16], cc[16];
#pragma unroll
    for (int k = 0; k < 16; ++k) {
        int i = t + k * 256;
        if (i < count) {
            int e = base + i;
            int r, c;
            if (f) { r = ei[2 * e]; c = ei[2 * (E + e)]; }
            else   { r = ei[e];     c = ei[E + e]; }
            rr[k] = r; cc[k] = c;
            atomicAdd(&hist[c >> BSH], 1);
        }
    }
    __syncthreads();   // joins t0's scan and the histogram
    for (int i = t; i < NBKT; i += 256)
        if (hist[i] > 0) scur[i] = bb[i] + atomicAdd(&bcur[i], hist[i]);
    __syncthreads();
#pragma unroll
    for (int k = 0; k < 16; ++k) {
        int i = t + k * 256;
        if (i < count) {
            int b = cc[k] >> BSH;
            int pos = atomicAdd(&scur[b], 1);
            pairs[pos] = (uint2){(uint)rr[k], (uint)cc[k]};
        }
    }
}

// one block per bucket (392 blocks, 256 nodes each): LDS histogram + scan ->
// ptr0/cnt/dinv (1 node/thread), then scatter srow with LDS atomics only.
__global__ __launch_bounds__(256) void k_cnt(const uint2* __restrict__ pairs,
                                             const int* __restrict__ bktot,
                                             int* __restrict__ ptr0,
                                             int* __restrict__ cnt,
                                             float* __restrict__ dinv,
                                             int* __restrict__ srow) {
    __shared__ int sbt[NBKT];
    __shared__ int hist[256], scur[256], ls[256];
    __shared__ int se0, se1;
    int b = blockIdx.x;
    int t = threadIdx.x;
    for (int i = t; i < NBKT; i += 256) sbt[i] = bktot[i];
    hist[t] = 0;
    __syncthreads();
    if (t == 0) {
        int run = 0;
        for (int i = 0; i < b; ++i) run += sbt[i];
        se0 = run; se1 = run + sbt[b];
    }
    __syncthreads();
    int e0 = se0, e1 = se1;
    int nodebase = b << BSH;
    for (int i = e0 + t; i < e1; i += 256)
        atomicAdd(&hist[(int)pairs[i].y - nodebase], 1);
    __syncthreads();
    int c1 = hist[t];
    ls[t] = c1;
    __syncthreads();
    for (int o = 1; o < 256; o <<= 1) {
        int v = (t >= o) ? ls[t - o] : 0;
        __syncthreads();
        ls[t] += v;
        __syncthreads();
    }
    int run = ls[t] - c1 + e0;
    int idx = nodebase + t;
    if (idx < NN) {
        ptr0[idx] = run;
        cnt[idx] = c1;
        dinv[idx] = c1 > 0 ? rsqrtf((float)c1) : 0.f;
    }
    scur[t] = run;
    __syncthreads();
    for (int i = e0 + t; i < e1; i += 256) {
        uint2 p = pairs[i];
        int pos = atomicAdd(&scur[(int)p.y - nodebase], 1);
        srow[pos] = (int)p.x;
    }
}

// FUSED gather + GEMM + stats. Block = 8 waves = 512 thr, 64-row tile.
// Gather: quad-per-node (R8 scheme) + PER-TILE DEGREE SORT: nodes ranked by
// degree in LDS; each quad-group takes 4 adjacent sorted nodes, so the
// group's max degree ~= its mean (padding waste 65% -> ~20%). Edge order per
// node unchanged -> bitwise-identical accumulation.
__global__ __launch_bounds__(512, 4) void k_gg(const uint* __restrict__ xb,
                                               const int* __restrict__ srow,
                                               const int* __restrict__ ptr0,
                                               const int* __restrict__ cnt,
                                               const float* __restrict__ dinv,
                                               const ushort* __restrict__ wb,
                                               ushort* __restrict__ hb,
                                               float* __restrict__ csr,
                                               float* __restrict__ cqr) {
    __shared__ ushort sA[64 * LDA];            // 17.4 KB
    __shared__ float cp[8][64], cq[8][64];     // 4 KB
    __shared__ int sS[64], sK[64], sPerm[64];
    __shared__ float sD[64];
    int t = threadIdx.x;
    int wave = t >> 6, lane = t & 63;
    int quad = lane >> 4, l16 = lane & 15;
    uint rowbase = (uint)blockIdx.x * 64;
    const uint4* xb4 = (const uint4*)xb;

    if (t < 64) {                               // prefetch node meta into LDS
        int node = (int)rowbase + t;
        bool v = node < NN;
        sS[t] = v ? ptr0[node] : 0;
        sK[t] = v ? cnt[node] : 0;
        sD[t] = v ? dinv[node] : 0.f;
    }
    __syncthreads();
    if (t < 64) {                               // rank-sort by degree (desc)
        int d = sK[t];
        int rank = 0;
#pragma unroll 16
        for (int j = 0; j < 64; ++j) {
            int dj = sK[j];
            rank += (dj > d) || (dj == d && j < t);
        }
        sPerm[rank] = t;
    }
    __syncthreads();

    for (int bt = 0; bt < 2; ++bt) {           // 2 batches: group g = bt*8+wave
        int g = bt * 8 + wave;
        int ni = sPerm[4 * g + quad];          // this quad's node
        int s_here = sS[ni];
        int k_here = sK[ni];
        float d_here = sD[ni];
        int km = sK[sPerm[4 * g]];             // largest degree in group (sorted)

        float ax0 = 0.f, ax1 = 0.f, ax2 = 0.f, ax3 = 0.f;
        float ax4 = 0.f, ax5 = 0.f, ax6 = 0.f, ax7 = 0.f;

        for (int base = 0; base < km; base += 16) {
            int rem = k_here - base;           // quad-uniform
            int rj = 0;
            if (l16 < rem) rj = srow[s_here + base + l16];
            int jend = km - base; jend = jend > 16 ? 16 : jend;
            for (int j = 0; j < jend; j += 4) {
#pragma unroll
                for (int u = 0; u < 4; ++u) {
                    int jj = j + u;            // jj < 16 always
                    int rsel = __shfl(rj, (lane & 48) + jj);
                    float w = dinv[rsel];      // quad-uniform load
                    uint4 v = xb4[((uint)rsel << 4) + (uint)l16];
                    w = (jj < rem) ? w : 0.f;  // tail mask (rsel=0 row is safe)
                    ax0 = fmaf(w, blo(v.x), ax0); ax1 = fmaf(w, bhi(v.x), ax1);
                    ax2 = fmaf(w, blo(v.y), ax2); ax3 = fmaf(w, bhi(v.y), ax3);
                    ax4 = fmaf(w, blo(v.z), ax4); ax5 = fmaf(w, bhi(v.z), ax5);
                    ax6 = fmaf(w, blo(v.w), ax6); ax7 = fmaf(w, bhi(v.w), ax7);
                }
            }
        }
        uint4 o;
        o.x = (uint)f2b(d_here * ax0) | ((uint)f2b(d_here * ax1) << 16);
        o.y = (uint)f2b(d_here * ax2) | ((uint)f2b(d_here * ax3) << 16);
        o.z = (uint)f2b(d_here * ax4) | ((uint)f2b(d_here * ax5) << 16);
        o.w = (uint)f2b(d_here * ax6) | ((uint)f2b(d_here * ax7) << 16);
        *(uint4*)(sA + ni * LDA + l16 * 8) = o;            // zeros for OOB
    }
    __syncthreads();

    // --- GEMM: wave = row-group (wave&3) x ct-half (wave>>2) ---
    int rg = wave & 3, chh = wave >> 2;
    bf16x8 Af[4];
#pragma unroll
    for (int ks = 0; ks < 4; ++ks)
        Af[ks] = __builtin_bit_cast(
            bf16x8, *(const uint4*)(sA + (rg * 16 + l16) * LDA + ks * 32 + quad * 8));

#pragma unroll
    for (int c = 0; c < 4; ++c) {
        int ctg = chh * 4 + c;
        bf16x8 Bf[4];
#pragma unroll
        for (int ks = 0; ks < 4; ++ks)
            Bf[ks] = __builtin_bit_cast(
                bf16x8,
                *(const uint4*)(wb + (uint)(ctg * 16 + l16) * 128 + ks * 32 + quad * 8));
        f32x4 acc = (f32x4){0.f, 0.f, 0.f, 0.f};
#pragma unroll
        for (int ks = 0; ks < 4; ++ks)
            acc = __builtin_amdgcn_mfma_f32_16x16x32_bf16(Af[ks], Bf[ks], acc, 0, 0, 0);
        float ss = 0.f, qq = 0.f;
#pragma unroll
        for (int r = 0; r < 4; ++r) {
            float v = acc[r];
            ss += v; qq += v * v;
            uint row = rowbase + rg * 16 + quad * 4 + r;
            if (row < NN) hb[row * 128u + (uint)(ctg * 16 + l16)] = f2b(v);
        }
        ss += __shfl_xor(ss, 16); ss += __shfl_xor(ss, 32);
        qq += __shfl_xor(qq, 16); qq += __shfl_xor(qq, 32);
        if (quad == 0) { cp[wave][c * 16 + l16] = ss; cq[wave][c * 16 + l16] = qq; }
    }
    __syncthreads();
    if (t < 128) {
        int w0 = (t >> 6) * 4, lc = t & 63;
        float s = cp[w0][lc] + cp[w0 + 1][lc] + cp[w0 + 2][lc] + cp[w0 + 3][lc];
        float q = cq[w0][lc] + cq[w0 + 1][lc] + cq[w0 + 2][lc] + cq[w0 + 3][lc];
        int rep = ((int)blockIdx.x & (NREP - 1)) * 128 + t;
        atomicAdd(&csr[rep], s);
        atomicAdd(&cqr[rep], q);
    }
}

// BN + relu + residual; folds the NREP stat replicas in LDS.
__global__ __launch_bounds__(256) void k_final(const uint* __restrict__ hb,
                                               const uint* __restrict__ xb,
                                               const float* __restrict__ gamma,
                                               const float* __restrict__ beta,
                                               const float* __restrict__ csr,
                                               const float* __restrict__ cqr,
                                               float* __restrict__ out, int out_size) {
    __shared__ float sa[128], sb[128];
    int t = threadIdx.x;
    const float invN = 1.0f / NN;
    if (t < 128) {
        float s = 0.f;
        for (int i = 0; i < NREP; ++i) s += csr[i * 128 + t];
        sa[t] = s * invN;
    } else {
        int c = t - 128;
        float s = 0.f;
        for (int i = 0; i < NREP; ++i) s += cqr[i * 128 + c];
        sb[c] = s * invN;
    }
    __syncthreads();
    if (t < 128) {
        float m = sa[t];
        float var = sb[t] - m * m;
        float inv = rsqrtf(var + BN_EPS);
        float A = inv * gamma[t];
        float B = beta[t] - m * A;
        sa[t] = A; sb[t] = B;
    }
    __syncthreads();

    int c0 = (t & 7) * 16;
    int u8 = blockIdx.x * 512 + t * 2;
    uint4 hv0 = ((const uint4*)hb)[u8], hv1 = ((const uint4*)hb)[u8 + 1];
    uint4 xv0 = ((const uint4*)xb)[u8], xv1 = ((const uint4*)xb)[u8 + 1];
    uint hu[8] = {hv0.x, hv0.y, hv0.z, hv0.w, hv1.x, hv1.y, hv1.z, hv1.w};
    uint xu[8] = {xv0.x, xv0.y, xv0.z, xv0.w, xv1.x, xv1.y, xv1.z, xv1.w};
    float res[16];
#pragma unroll
    for (int p = 0; p < 8; ++p) {
        int c = c0 + p * 2;
        float h0 = blo(hu[p]), h1 = bhi(hu[p]);
        float x0 = blo(xu[p]), x1 = bhi(xu[p]);
        res[2 * p]     = fmaxf(fmaf(h0, sa[c],     sb[c]),     0.f) + x0;
        res[2 * p + 1] = fmaxf(fmaf(h1, sa[c + 1], sb[c + 1]), 0.f) + x1;
    }
    float4* o4 = (float4*)out;
    int ob = blockIdx.x * 1024 + t * 4;
#pragma unroll
    for (int q = 0; q < 4; ++q)
        o4[ob + q] = (float4){res[4 * q], res[4 * q + 1], res[4 * q + 2], res[4 * q + 3]};
    if (blockIdx.x == 0 && t == 0 && out_size > ND) out[ND] = 0.0f;
}

extern "C" void kernel_launch(void* const* d_in, const int* in_sizes, int n_in,
                              void* d_out, int out_size, void* d_ws, size_t ws_size,
                              hipStream_t stream) {
    const float* x     = (const float*)d_in[0];
    const int*   ei    = (const int*)d_in[1];
    const float* W     = (const float*)d_in[2];
    const float* gamma = (const float*)d_in[4];
    const float* beta  = (const float*)d_in[5];
    float* ws = (float*)d_ws;
    float* out = (float*)d_out;

    uint*   region0  = (uint*)ws;                      // pairs, then hb
    uint*   xb       = region0 + ND / 2;
    float*  csr      = (float*)(xb + ND / 2);          // 16*128
    float*  cqr      = csr + NREP * 128;               // 16*128
    int*    bktot    = (int*)(cqr + NREP * 128);       // 512 (zeroed)
    int*    bcur     = bktot + 512;                    // 512 (zeroed)
    int*    cnt      = bcur + 512;                     // NN
    int*    ptr0     = cnt + NN;                       // NN
    float*  dinv     = (float*)(ptr0 + NN);            // NN
    int*    srow     = (int*)(dinv + NN);              // E

    int E = in_sizes[1] / 2;
    uint* wb = (uint*)(srow + E);
    uint2* pairs = (uint2*)region0;

    int nbc = (ND / 8 + (DD * DD) / 8 + 255) / 256;
    int nbin = (E + EPB - 1) / EPB;

    hipMemsetAsync(csr, 0, (size_t)(2 * NREP * 128 + 1024) * 4, stream);
    k_prep<<<nbin + nbc, 256, 0, stream>>>(ei, bktot, E, nbin, x, xb, W, wb);
    k_bin<<<nbin, 256, 0, stream>>>(ei, bktot, bcur, pairs, E);
    k_cnt<<<NBKT, 256, 0, stream>>>(pairs, bktot, ptr0, cnt, dinv, srow);
    k_gg<<<NT, 512, 0, stream>>>(xb, srow, ptr0, cnt, dinv, (const ushort*)wb,
                                 (ushort*)region0, csr, cqr);
    k_final<<<ND / 4096, 256, 0, stream>>>(region0, xb, gamma, beta, csr, cqr,
                                           out, out_size);
}

// Round 11
// 203.271 us; speedup vs baseline: 1.1406x; 1.0982x over previous
//
#include <hip/hip_runtime.h>
#include <cstddef>

#define NN 100000
#define DD 128
#define ND (NN * DD)
#define BN_EPS 1e-5f
#define LDA 136                // LDS A row stride in bf16 elems (272 B, 16B-aligned)
#define NREP 16                // stats-accumulator replicas
#define NBKT 392               // scatter buckets: 256 nodes each (392*256 >= NN)
#define BSH 8                  // bucket = col >> 8
#define CAP 4096               // fixed pairs/srow capacity per bucket (mean 2048, +45 sigma)
#define EPB 4096               // edges per k_bin block
#define NT ((NN + 63) / 64)    // 1563 tiles of 64 rows

typedef __bf16 bf16_t;
typedef bf16_t bf16x8 __attribute__((ext_vector_type(8)));
typedef float f32x4 __attribute__((ext_vector_type(4)));
typedef unsigned int uint;
typedef unsigned short ushort;

// ws 4-byte-slot layout:
//   [0, ND/2)            region0: pairs (uint2, bucket-segmented CAP each) pre-gg; hb after
//   [ND/2, ND)           xb   (bf16 x)
//   base3 = ND:
//   csr[16*128], cqr[16*128], bcur[512]  (memset zeroes all),
//   cnt[NN], ptr0[NN], dinv[NN], srow[NBKT*CAP], wb[4096 uints]

__device__ __forceinline__ ushort f2b(float f) {
    uint u = __builtin_bit_cast(uint, f);
    u += 0x7FFFu + ((u >> 16) & 1u);          // RNE
    return (ushort)(u >> 16);
}
__device__ __forceinline__ float b2f(uint s) {
    return __builtin_bit_cast(float, s << 16);
}
__device__ __forceinline__ float blo(uint u) {          // low bf16 -> f32
    return __builtin_bit_cast(float, u << 16);
}
__device__ __forceinline__ float bhi(uint u) {          // high bf16 -> f32
    return __builtin_bit_cast(float, u & 0xFFFF0000u);
}

// int64 edge_index => high word of every entry is 0 (ids < 100000).
__device__ __forceinline__ int detect_i64(const int* __restrict__ ei) {
    __shared__ int sflag;
    int t = threadIdx.x;
    if (t < 64) {
        int hi = ei[2 * t + 1];
        unsigned long long b = __ballot(hi == 0);
        if (t == 0) sflag = (b == ~0ull) ? 1 : 0;
    }
    __syncthreads();
    return sflag;
}

// dual-role: blocks [0, nbin) partition edges into fixed-capacity buckets
// (LDS histogram + one global atomic per (block,bucket) + private runs);
// blocks [nbin, ...) pack x and W to bf16. No bktot pass needed.
__global__ __launch_bounds__(256) void k_bin(const int* __restrict__ ei,
                                             int* __restrict__ bcur,
                                             uint2* __restrict__ pairs, int E, int nbin,
                                             const float* __restrict__ x,
                                             uint* __restrict__ xb,
                                             const float* __restrict__ W,
                                             uint* __restrict__ wb) {
    if ((int)blockIdx.x >= nbin) {             // pack role
        int i = ((int)blockIdx.x - nbin) * 256 + threadIdx.x;
        const float* src;
        uint* dst;
        int j;
        if (i < ND / 8) { src = x; dst = xb; j = i; }
        else { j = i - ND / 8; if (j >= (DD * DD) / 8) return; src = W; dst = wb; }
        const float4* s4 = (const float4*)src;
        float4 a = s4[2 * j], b = s4[2 * j + 1];
        uint4 o;
        o.x = (uint)f2b(a.x) | ((uint)f2b(a.y) << 16);
        o.y = (uint)f2b(a.z) | ((uint)f2b(a.w) << 16);
        o.z = (uint)f2b(b.x) | ((uint)f2b(b.y) << 16);
        o.w = (uint)f2b(b.z) | ((uint)f2b(b.w) << 16);
        ((uint4*)dst)[j] = o;
        return;
    }
    int f = detect_i64(ei);
    __shared__ int hist[NBKT], scur[NBKT];
    int t = threadIdx.x;
    for (int i = t; i < NBKT; i += 256) hist[i] = 0;
    __syncthreads();
    int base = blockIdx.x * EPB;
    int count = min(EPB, E - base);
    int rr[16], cc[16];
#pragma unroll
    for (int k = 0; k < 16; ++k) {
        int i = t + k * 256;
        if (i < count) {
            int e = base + i;
            int r, c;
            if (f) { r = ei[2 * e]; c = ei[2 * (E + e)]; }
            else   { r = ei[e];     c = ei[E + e]; }
            rr[k] = r; cc[k] = c;
            atomicAdd(&hist[c >> BSH], 1);
        }
    }
    __syncthreads();
    for (int i = t; i < NBKT; i += 256)
        if (hist[i] > 0) scur[i] = i * CAP + atomicAdd(&bcur[i], hist[i]);
    __syncthreads();
#pragma unroll
    for (int k = 0; k < 16; ++k) {
        int i = t + k * 256;
        if (i < count) {
            int b = cc[k] >> BSH;
            int pos = atomicAdd(&scur[b], 1);
            pairs[pos] = (uint2){(uint)rr[k], (uint)cc[k]};
        }
    }
}

// one block per bucket (392 blocks, 256 nodes each): LDS histogram of the
// bucket's pairs segment, LDS scan -> ptr0/cnt/dinv (1 node/thread), then
// scatter srow (bucket-segmented, base b*CAP) with LDS atomics only.
__global__ __launch_bounds__(256) void k_cnt(const uint2* __restrict__ pairs,
                                             const int* __restrict__ bcur,
                                             int* __restrict__ ptr0,
                                             int* __restrict__ cnt,
                                             float* __restrict__ dinv,
                                             int* __restrict__ srow) {
    __shared__ int hist[256], scur[256], ls[256];
    int b = blockIdx.x;
    int t = threadIdx.x;
    int e0 = b * CAP;
    int e1 = e0 + bcur[b];
    int nodebase = b << BSH;
    hist[t] = 0;
    __syncthreads();
    for (int i = e0 + t; i < e1; i += 256)
        atomicAdd(&hist[(int)pairs[i].y - nodebase], 1);
    __syncthreads();
    int c1 = hist[t];
    ls[t] = c1;
    __syncthreads();
    for (int o = 1; o < 256; o <<= 1) {
        int v = (t >= o) ? ls[t - o] : 0;
        __syncthreads();
        ls[t] += v;
        __syncthreads();
    }
    int run = ls[t] - c1 + e0;                 // position inside bucket segment
    int idx = nodebase + t;
    if (idx < NN) {
        ptr0[idx] = run;
        cnt[idx] = c1;
        dinv[idx] = c1 > 0 ? rsqrtf((float)c1) : 0.f;
    }
    scur[t] = run;
    __syncthreads();
    for (int i = e0 + t; i < e1; i += 256) {
        uint2 p = pairs[i];
        int pos = atomicAdd(&scur[(int)p.y - nodebase], 1);
        srow[pos] = (int)p.x;
    }
}

// FUSED gather + GEMM + stats. Block = 8 waves = 512 thr, 64-row tile.
// Gather: quad-per-node (R8 proven scheme) — 4 nodes/wave at a time, 16
// lanes each; one uint4 load instr fetches 4 source rows (1 KB); dinv is a
// quad-uniform load; edge broadcast via per-lane-indexed shfl.
__global__ __launch_bounds__(512, 4) void k_gg(const uint* __restrict__ xb,
                                               const int* __restrict__ srow,
                                               const int* __restrict__ ptr0,
                                               const int* __restrict__ cnt,
                                               const float* __restrict__ dinv,
                                               const ushort* __restrict__ wb,
                                               ushort* __restrict__ hb,
                                               float* __restrict__ csr,
                                               float* __restrict__ cqr) {
    __shared__ ushort sA[64 * LDA];            // 17.4 KB
    __shared__ float cp[8][64], cq[8][64];     // 4 KB
    int t = threadIdx.x;
    int wave = t >> 6, lane = t & 63;
    int quad = lane >> 4, l16 = lane & 15;
    uint rowbase = (uint)blockIdx.x * 64;
    const uint4* xb4 = (const uint4*)xb;

    // wave owns rows wave*8 .. wave*8+7; lanes 0..7 hold per-node meta
    int mn = (int)rowbase + wave * 8 + (lane & 7);
    int sv = 0, kv = 0;
    float dv = 0.f;
    if (lane < 8 && mn < NN) { sv = ptr0[mn]; kv = cnt[mn]; dv = dinv[mn]; }

    for (int bt = 0; bt < 2; ++bt) {           // 2 batches of 4 nodes
        int ni = bt * 4 + quad;                // this quad's node (0..7)
        int s_here = __shfl(sv, ni);
        int k_here = __shfl(kv, ni);
        float d_here = __shfl(dv, ni);
        int km = max(k_here, __shfl_xor(k_here, 16));
        km = max(km, __shfl_xor(km, 32));      // max degree over the 4 quads

        float ax0 = 0.f, ax1 = 0.f, ax2 = 0.f, ax3 = 0.f;
        float ax4 = 0.f, ax5 = 0.f, ax6 = 0.f, ax7 = 0.f;

        for (int base = 0; base < km; base += 16) {
            int rem = k_here - base;           // quad-uniform
            int rj = 0;
            if (l16 < rem) rj = srow[s_here + base + l16];
            int jend = km - base; jend = jend > 16 ? 16 : jend;
            for (int j = 0; j < jend; j += 4) {
#pragma unroll
                for (int u = 0; u < 4; ++u) {
                    int jj = j + u;            // jj < 16 always
                    int rsel = __shfl(rj, (lane & 48) + jj);
                    float w = dinv[rsel];      // quad-uniform load
                    uint4 v = xb4[((uint)rsel << 4) + (uint)l16];
                    w = (jj < rem) ? w : 0.f;  // tail mask (rsel=0 row is safe)
                    ax0 = fmaf(w, blo(v.x), ax0); ax1 = fmaf(w, bhi(v.x), ax1);
                    ax2 = fmaf(w, blo(v.y), ax2); ax3 = fmaf(w, bhi(v.y), ax3);
                    ax4 = fmaf(w, blo(v.z), ax4); ax5 = fmaf(w, bhi(v.z), ax5);
                    ax6 = fmaf(w, blo(v.w), ax6); ax7 = fmaf(w, bhi(v.w), ax7);
                }
            }
        }
        uint4 o;
        o.x = (uint)f2b(d_here * ax0) | ((uint)f2b(d_here * ax1) << 16);
        o.y = (uint)f2b(d_here * ax2) | ((uint)f2b(d_here * ax3) << 16);
        o.z = (uint)f2b(d_here * ax4) | ((uint)f2b(d_here * ax5) << 16);
        o.w = (uint)f2b(d_here * ax6) | ((uint)f2b(d_here * ax7) << 16);
        *(uint4*)(sA + (wave * 8 + ni) * LDA + l16 * 8) = o;   // zeros for OOB
    }
    __syncthreads();

    // --- GEMM: wave = row-group (wave&3) x ct-half (wave>>2) ---
    int rg = wave & 3, chh = wave >> 2;
    bf16x8 Af[4];
#pragma unroll
    for (int ks = 0; ks < 4; ++ks)
        Af[ks] = __builtin_bit_cast(
            bf16x8, *(const uint4*)(sA + (rg * 16 + l16) * LDA + ks * 32 + quad * 8));

#pragma unroll
    for (int c = 0; c < 4; ++c) {
        int ctg = chh * 4 + c;
        bf16x8 Bf[4];
#pragma unroll
        for (int ks = 0; ks < 4; ++ks)
            Bf[ks] = __builtin_bit_cast(
                bf16x8,
                *(const uint4*)(wb + (uint)(ctg * 16 + l16) * 128 + ks * 32 + quad * 8));
        f32x4 acc = (f32x4){0.f, 0.f, 0.f, 0.f};
#pragma unroll
        for (int ks = 0; ks < 4; ++ks)
            acc = __builtin_amdgcn_mfma_f32_16x16x32_bf16(Af[ks], Bf[ks], acc, 0, 0, 0);
        float ss = 0.f, qq = 0.f;
#pragma unroll
        for (int r = 0; r < 4; ++r) {
            float v = acc[r];
            ss += v; qq += v * v;
            uint row = rowbase + rg * 16 + quad * 4 + r;
            if (row < NN) hb[row * 128u + (uint)(ctg * 16 + l16)] = f2b(v);
        }
        ss += __shfl_xor(ss, 16); ss += __shfl_xor(ss, 32);
        qq += __shfl_xor(qq, 16); qq += __shfl_xor(qq, 32);
        if (quad == 0) { cp[wave][c * 16 + l16] = ss; cq[wave][c * 16 + l16] = qq; }
    }
    __syncthreads();
    if (t < 128) {
        int w0 = (t >> 6) * 4, lc = t & 63;
        float s = cp[w0][lc] + cp[w0 + 1][lc] + cp[w0 + 2][lc] + cp[w0 + 3][lc];
        float q = cq[w0][lc] + cq[w0 + 1][lc] + cq[w0 + 2][lc] + cq[w0 + 3][lc];
        int rep = ((int)blockIdx.x & (NREP - 1)) * 128 + t;
        atomicAdd(&csr[rep], s);
        atomicAdd(&cqr[rep], q);
    }
}

// BN + relu + residual; folds the NREP stat replicas in LDS.
__global__ __launch_bounds__(256) void k_final(const uint* __restrict__ hb,
                                               const uint* __restrict__ xb,
                                               const float* __restrict__ gamma,
                                               const float* __restrict__ beta,
                                               const float* __restrict__ csr,
                                               const float* __restrict__ cqr,
                                               float* __restrict__ out, int out_size) {
    __shared__ float sa[128], sb[128];
    int t = threadIdx.x;
    const float invN = 1.0f / NN;
    if (t < 128) {
        float s = 0.f;
        for (int i = 0; i < NREP; ++i) s += csr[i * 128 + t];
        sa[t] = s * invN;
    } else {
        int c = t - 128;
        float s = 0.f;
        for (int i = 0; i < NREP; ++i) s += cqr[i * 128 + c];
        sb[c] = s * invN;
    }
    __syncthreads();
    if (t < 128) {
        float m = sa[t];
        float var = sb[t] - m * m;
        float inv = rsqrtf(var + BN_EPS);
        float A = inv * gamma[t];
        float B = beta[t] - m * A;
        sa[t] = A; sb[t] = B;
    }
    __syncthreads();

    int c0 = (t & 7) * 16;
    int u8 = blockIdx.x * 512 + t * 2;
    uint4 hv0 = ((const uint4*)hb)[u8], hv1 = ((const uint4*)hb)[u8 + 1];
    uint4 xv0 = ((const uint4*)xb)[u8], xv1 = ((const uint4*)xb)[u8 + 1];
    uint hu[8] = {hv0.x, hv0.y, hv0.z, hv0.w, hv1.x, hv1.y, hv1.z, hv1.w};
    uint xu[8] = {xv0.x, xv0.y, xv0.z, xv0.w, xv1.x, xv1.y, xv1.z, xv1.w};
    float res[16];
#pragma unroll
    for (int p = 0; p < 8; ++p) {
        int c = c0 + p * 2;
        float h0 = blo(hu[p]), h1 = bhi(hu[p]);
        float x0 = blo(xu[p]), x1 = bhi(xu[p]);
        res[2 * p]     = fmaxf(fmaf(h0, sa[c],     sb[c]),     0.f) + x0;
        res[2 * p + 1] = fmaxf(fmaf(h1, sa[c + 1], sb[c + 1]), 0.f) + x1;
    }
    float4* o4 = (float4*)out;
    int ob = blockIdx.x * 1024 + t * 4;
#pragma unroll
    for (int q = 0; q < 4; ++q)
        o4[ob + q] = (float4){res[4 * q], res[4 * q + 1], res[4 * q + 2], res[4 * q + 3]};
    if (blockIdx.x == 0 && t == 0 && out_size > ND) out[ND] = 0.0f;
}

extern "C" void kernel_launch(void* const* d_in, const int* in_sizes, int n_in,
                              void* d_out, int out_size, void* d_ws, size_t ws_size,
                              hipStream_t stream) {
    const float* x     = (const float*)d_in[0];
    const int*   ei    = (const int*)d_in[1];
    const float* W     = (const float*)d_in[2];
    const float* gamma = (const float*)d_in[4];
    const float* beta  = (const float*)d_in[5];
    float* ws = (float*)d_ws;
    float* out = (float*)d_out;

    uint*   region0  = (uint*)ws;                      // pairs, then hb
    uint*   xb       = region0 + ND / 2;
    float*  csr      = (float*)(xb + ND / 2);          // 16*128
    float*  cqr      = csr + NREP * 128;               // 16*128
    int*    bcur     = (int*)(cqr + NREP * 128);       // 512 (zeroed)
    int*    cnt      = bcur + 512;                     // NN
    int*    ptr0     = cnt + NN;                       // NN
    float*  dinv     = (float*)(ptr0 + NN);            // NN
    int*    srow     = (int*)(dinv + NN);              // NBKT*CAP

    int E = in_sizes[1] / 2;
    uint* wb = (uint*)(srow + NBKT * CAP);
    uint2* pairs = (uint2*)region0;                    // NBKT*CAP*2 uints <= ND/2

    int nbc = (ND / 8 + (DD * DD) / 8 + 255) / 256;
    int nbin = (E + EPB - 1) / EPB;

    hipMemsetAsync(csr, 0, (size_t)(2 * NREP * 128 + 512) * 4, stream);
    k_bin<<<nbin + nbc, 256, 0, stream>>>(ei, bcur, pairs, E, nbin, x, xb, W, wb);
    k_cnt<<<NBKT, 256, 0, stream>>>(pairs, bcur, ptr0, cnt, dinv, srow);
    k_gg<<<NT, 512, 0, stream>>>(xb, srow, ptr0, cnt, dinv, (const ushort*)wb,
                                 (ushort*)region0, csr, cqr);
    k_final<<<ND / 4096, 256, 0, stream>>>(region0, xb, gamma, beta, csr, cqr,
                                           out, out_size);
}